// Round 8
// baseline (684.522 us; speedup 1.0000x reference)
//
#include <hip/hip_runtime.h>
#include <math.h>

#define BB 4
#define NN 8192
#define PP 32768
#define KNN 16

typedef float f32x2 __attribute__((ext_vector_type(2)));
typedef float f32x4 __attribute__((ext_vector_type(4)));

__device__ __forceinline__ f32x2 pk_mul(f32x2 a, f32x2 b) {
  f32x2 d; asm("v_pk_mul_f32 %0, %1, %2" : "=v"(d) : "v"(a), "v"(b)); return d;
}
__device__ __forceinline__ f32x2 pk_add(f32x2 a, f32x2 b) {
  f32x2 d; asm("v_pk_add_f32 %0, %1, %2" : "=v"(d) : "v"(a), "v"(b)); return d;
}

// ---------------- embed1: h1 = pts @ w1 + b1  [P,64], fused per-channel stats ----------------
__global__ __launch_bounds__(256) void k_embed1(const float* __restrict__ pts,
    const float* __restrict__ w1, const float* __restrict__ b1, float* __restrict__ h1,
    float* __restrict__ gsum, float* __restrict__ gss)
{
  int tid = threadIdx.x;
  int c = tid & 63, g = tid >> 6;
  float wx = w1[c], wy = w1[64 + c], wz = w1[128 + c], bc = b1[c];
  int base = blockIdx.x * 256;
  float s = 0.f, ss = 0.f;
  #pragma unroll 4
  for (int i = 0; i < 64; ++i) {
    int p = base + g + i * 4;
    float px = pts[p*3+0], py = pts[p*3+1], pz = pts[p*3+2];
    float h = fmaf(pz, wz, fmaf(py, wy, fmaf(px, wx, bc)));
    h1[(size_t)p*64 + c] = h;
    s += h; ss = fmaf(h, h, ss);
  }
  __shared__ float ls[256], lq[256];
  ls[tid] = s; lq[tid] = ss;
  __syncthreads();
  if (tid < 64) {
    float a  = ls[tid] + ls[tid+64] + ls[tid+128] + ls[tid+192];
    float b2 = lq[tid] + lq[tid+64] + lq[tid+128] + lq[tid+192];
    atomicAdd(gsum + tid, a);
    atomicAdd(gss  + tid, b2);
  }
}

// ---------------- prep for kNN: pair-transposed layout, 16-slot chunks ----------------
__global__ __launch_bounds__(256) void k_prep(const float* __restrict__ pts, float* __restrict__ pp)
{
  int t = blockIdx.x * 256 + threadIdx.x;    // 16384 pair slots
  int b = t >> 12, m = t & 4095;
  int c = m >> 4, l = m & 15;
  int jl = b * NN + c * 32 + l;
  int jh = jl + 16;
  float xl = pts[jl*3+0], yl = pts[jl*3+1], zl = pts[jl*3+2];
  float xh = pts[jh*3+0], yh = pts[jh*3+1], zh = pts[jh*3+2];
  float wl = __fadd_rn(__fadd_rn(__fmul_rn(xl,xl), __fmul_rn(yl,yl)), __fmul_rn(zl,zl));
  float wh = __fadd_rn(__fadd_rn(__fmul_rn(xh,xh), __fmul_rn(yh,yh)), __fmul_rn(zh,zh));
  float* o = pp + (size_t)t * 8;
  *(float4*)(o + 0) = make_float4(xl, xh, yl, yh);
  *(float4*)(o + 4) = make_float4(zl, zh, wl, wh);
}

// ---------------- generic projection: out = relu(bn(in)) @ W (+bias), fused stats ----------
template<int K, int COUT, bool STATS>
__global__ __launch_bounds__(256) void k_proj(const float* __restrict__ in,
    const float* __restrict__ gsumI, const float* __restrict__ gssI,
    const float* __restrict__ gamma, const float* __restrict__ beta,
    const float* __restrict__ W0, const float* __restrict__ W1, const float* __restrict__ W2,
    const float* __restrict__ B0, const float* __restrict__ B1, const float* __restrict__ B2,
    float* __restrict__ O0, float* __restrict__ O1, float* __restrict__ O2,
    float* __restrict__ gsumO, float* __restrict__ gssO)
{
  constexpr int PTS = 64;
  constexpr int CW = 8;
  constexpr int CG = COUT / CW;        // channel groups: 8 (COUT=64) or 16 (COUT=128)
  constexpr int PW = PTS * CG / 256;   // points per thread: 2 or 4
  const float* W  = (blockIdx.y == 0) ? W0 : (blockIdx.y == 1) ? W1 : W2;
  const float* Bb = (blockIdx.y == 0) ? B0 : (blockIdx.y == 1) ? B1 : B2;
  float*       O  = (blockIdx.y == 0) ? O0 : (blockIdx.y == 1) ? O1 : O2;
  __shared__ float xs[PTS][K + 1];
  __shared__ float scs[K], shs[K];
  int tid = threadIdx.x;
  if (tid < K) {                        // inline BN finalize (replaces k_finalize kernel)
    float mean = gsumI[tid] * (1.0f / PP);
    float var  = gssI[tid] * (1.0f / PP) - mean * mean;
    float s = gamma[tid] / sqrtf(var + 1e-5f);
    scs[tid] = s;
    shs[tid] = beta[tid] - mean * s;
  }
  __syncthreads();
  int pbase = blockIdx.x * PTS;
  constexpr int T4 = PTS * K / 4;
  for (int i = tid; i < T4; i += 256) {
    int p = i / (K/4), k = (i % (K/4)) * 4;
    float4 v = *(const float4*)(in + (size_t)(pbase + p)*K + k);
    v.x = fmaxf(fmaf(v.x, scs[k+0], shs[k+0]), 0.f);
    v.y = fmaxf(fmaf(v.y, scs[k+1], shs[k+1]), 0.f);
    v.z = fmaxf(fmaf(v.z, scs[k+2], shs[k+2]), 0.f);
    v.w = fmaxf(fmaf(v.w, scs[k+3], shs[k+3]), 0.f);
    xs[p][k+0] = v.x; xs[p][k+1] = v.y; xs[p][k+2] = v.z; xs[p][k+3] = v.w;
  }
  __syncthreads();
  int cg = tid % CG, pg = tid / CG;
  int c0 = cg * CW, p0 = pg * PW;
  float acc[PW][CW];
  #pragma unroll
  for (int i = 0; i < PW; ++i) {
    #pragma unroll
    for (int j = 0; j < CW; ++j) acc[i][j] = 0.f;
  }
  #pragma unroll 4
  for (int k = 0; k < K; ++k) {
    float4 wa = *(const float4*)(W + (size_t)k*COUT + c0);
    float4 wb = *(const float4*)(W + (size_t)k*COUT + c0 + 4);
    #pragma unroll
    for (int i = 0; i < PW; ++i) {
      float x = xs[p0 + i][k];
      acc[i][0] = fmaf(x, wa.x, acc[i][0]);
      acc[i][1] = fmaf(x, wa.y, acc[i][1]);
      acc[i][2] = fmaf(x, wa.z, acc[i][2]);
      acc[i][3] = fmaf(x, wa.w, acc[i][3]);
      acc[i][4] = fmaf(x, wb.x, acc[i][4]);
      acc[i][5] = fmaf(x, wb.y, acc[i][5]);
      acc[i][6] = fmaf(x, wb.z, acc[i][6]);
      acc[i][7] = fmaf(x, wb.w, acc[i][7]);
    }
  }
  float bj[CW];
  #pragma unroll
  for (int j = 0; j < CW; ++j) bj[j] = Bb ? Bb[c0 + j] : 0.f;
  float sj[CW], qj[CW];
  #pragma unroll
  for (int j = 0; j < CW; ++j) { sj[j] = 0.f; qj[j] = 0.f; }
  #pragma unroll
  for (int i = 0; i < PW; ++i) {
    float* op = O + (size_t)(pbase + p0 + i)*COUT + c0;
    float o0 = acc[i][0]+bj[0], o1 = acc[i][1]+bj[1], o2 = acc[i][2]+bj[2], o3 = acc[i][3]+bj[3];
    float o4 = acc[i][4]+bj[4], o5 = acc[i][5]+bj[5], o6 = acc[i][6]+bj[6], o7 = acc[i][7]+bj[7];
    *(float4*)(op)     = make_float4(o0, o1, o2, o3);
    *(float4*)(op + 4) = make_float4(o4, o5, o6, o7);
    if (STATS) {
      sj[0]+=o0; sj[1]+=o1; sj[2]+=o2; sj[3]+=o3; sj[4]+=o4; sj[5]+=o5; sj[6]+=o6; sj[7]+=o7;
      qj[0]=fmaf(o0,o0,qj[0]); qj[1]=fmaf(o1,o1,qj[1]); qj[2]=fmaf(o2,o2,qj[2]); qj[3]=fmaf(o3,o3,qj[3]);
      qj[4]=fmaf(o4,o4,qj[4]); qj[5]=fmaf(o5,o5,qj[5]); qj[6]=fmaf(o6,o6,qj[6]); qj[7]=fmaf(o7,o7,qj[7]);
    }
  }
  if (STATS) {
    #pragma unroll
    for (int off = CG; off < 64; off <<= 1) {
      #pragma unroll
      for (int j = 0; j < CW; ++j) {
        sj[j] += __shfl_xor(sj[j], off);
        qj[j] += __shfl_xor(qj[j], off);
      }
    }
    __shared__ float ws[4][COUT], wq[4][COUT];
    int wid = tid >> 6, lane = tid & 63;
    if (lane < CG) {
      #pragma unroll
      for (int j = 0; j < CW; ++j) { ws[wid][lane*CW+j] = sj[j]; wq[wid][lane*CW+j] = qj[j]; }
    }
    __syncthreads();
    if (tid < COUT) {
      float a  = ws[0][tid] + ws[1][tid] + ws[2][tid] + ws[3][tid];
      float b2 = wq[0][tid] + wq[1][tid] + wq[2][tid] + wq[3][tid];
      atomicAdd(gsumO + tid, a);
      atomicAdd(gssO  + tid, b2);
    }
  }
}

// ---------------- kNN-16 v3 (measured best): 4 queries/wave, serial insert ----------------
__global__ __launch_bounds__(256, 8) void k_knn(const float* __restrict__ pp, int* __restrict__ idxout)
{
  int tid = threadIdx.x;
  int lane = tid & 63;
  int l16 = lane & 15;
  int g64 = lane & 48;                       // group base lane (0,16,32,48)
  int wv = (blockIdx.x * 256 + tid) >> 6;    // 8192 waves
  int b  = wv >> 11;                         // 2048 waves per batch
  int qbase = (wv * 4) & (NN - 1);
  int qc = qbase >> 5;                       // wave-uniform chunk containing all 4 queries
  int qr = (qbase & 31) + (lane >> 4);       // query position within chunk (per group)
  const float* pb = pp + (size_t)b * (NN * 4);

  // query coords (broadcast load within each group)
  float qx, qy, qz, qw;
  {
    int qslot = qc * 16 + (qr & 15);
    int qh = (qr >> 4) & 1;
    const float* qp = pb + (size_t)qslot * 8 + qh;
    qx = qp[0]; qy = qp[2]; qz = qp[4]; qw = qp[6];
  }
  f32x2 qx2; qx2.x = qx; qx2.y = qx;
  f32x2 qy2; qy2.x = qy; qy2.y = qy;
  f32x2 qz2; qz2.x = qz; qz2.y = qz;
  f32x2 qw2; qw2.x = qw; qw2.y = qw;

  int addr_push = (lane + 1) << 2;           // ds_permute: push lval to lane+1 (l16==0 ignores pv)
  int addr_tau  = (g64 + 15) << 2;           // ds_bpermute: read own group's list[15]

  float lval = 3.4e38f;  // list entry held by this lane (ascending in l16 within group)
  int   lidx = 0;
  float tau  = 3.4e38f;  // per-group 16th-best (replicated in group's lanes)

  // drain one half-chunk's candidates into the 4 group lists (parallel across groups)
  auto half_pass = [&](float d2, int jbase) {
    unsigned long long bal = __ballot(d2 < tau);
    if (bal) {
      unsigned slice = (unsigned)(bal >> g64) & 0xffffu;
      while (__ballot(slice != 0)) {
        bool live = slice != 0;
        int src = __ffs((int)slice) - 1;     // -1 when this group's slice is empty
        slice &= slice - 1;
        int ab = (g64 + (src & 15)) << 2;
        float v = __uint_as_float(__builtin_amdgcn_ds_bpermute(ab, __float_as_uint(d2)));
        if (!live) v = 3.4e38f;              // empty group -> no-op insert
        int jc = jbase + src;
        float pv = __uint_as_float(__builtin_amdgcn_ds_permute(addr_push, __float_as_uint(lval)));
        int   pi = __builtin_amdgcn_ds_permute(addr_push, lidx);
        bool atpos = (l16 == 0) || (pv <= v);
        if (lval > v) {
          lval = atpos ? v  : pv;
          lidx = atpos ? jc : pi;
        }
      }
      tau = __uint_as_float(__builtin_amdgcn_ds_bpermute(addr_tau, __float_as_uint(lval)));
    }
  };

  const float* cp = pb + (size_t)l16 * 8;

  // ---- chunk 0 (peeled): lo half seeds via bitonic sort, hi half via normal insert ----
  {
    f32x4 A  = *(const f32x4*)(cp + 0);
    f32x4 Bq = *(const f32x4*)(cp + 4);
    cp += 128;
    f32x2 xs = __builtin_shufflevector(A, A, 0, 1);
    f32x2 ys = __builtin_shufflevector(A, A, 2, 3);
    f32x2 zs = __builtin_shufflevector(Bq, Bq, 0, 1);
    f32x2 ws = __builtin_shufflevector(Bq, Bq, 2, 3);
    f32x2 dot = pk_add(pk_add(pk_mul(qx2, xs), pk_mul(qy2, ys)), pk_mul(qz2, zs));
    f32x2 s2  = pk_add(qw2, ws);
    f32x2 t2  = pk_add(dot, dot);
    float d2lo = __fsub_rn(s2.x, t2.x);
    float d2hi = __fsub_rn(s2.y, t2.y);
    if (qc == 0) {                            // self-exclusion (wave-uniform branch)
      bool lo = qr < 16;
      int  tl = lo ? qr : qr - 16;
      if (l16 == tl) { if (lo) d2lo = 3.4e38f; else d2hi = 3.4e38f; }
    }
    // 16-lane bitonic sort of (d2lo, j=l16), ascending by (d2, j) within each group
    float v = d2lo; int ix = l16;
    #pragma unroll
    for (int k = 2; k <= 16; k <<= 1) {
      #pragma unroll
      for (int j = k >> 1; j >= 1; j >>= 1) {
        float ov = __shfl_xor(v, j, 16);
        int   oi = __shfl_xor(ix, j, 16);
        bool up    = (l16 & k) == 0;
        bool lower = (l16 & j) == 0;
        bool lt = (ov < v) || (ov == v && oi < ix);
        if ((up == lower) ? lt : !lt) { v = ov; ix = oi; }
      }
    }
    lval = v; lidx = ix;
    tau = __uint_as_float(__builtin_amdgcn_ds_bpermute(addr_tau, __float_as_uint(lval)));
    half_pass(d2hi, 16);
  }

  // ---- chunks 1..255 ----
  for (int c = 1; c < 256; ++c) {
    f32x4 A  = *(const f32x4*)(cp + 0);
    f32x4 Bq = *(const f32x4*)(cp + 4);
    cp += 128;
    f32x2 xs = __builtin_shufflevector(A, A, 0, 1);
    f32x2 ys = __builtin_shufflevector(A, A, 2, 3);
    f32x2 zs = __builtin_shufflevector(Bq, Bq, 0, 1);
    f32x2 ws = __builtin_shufflevector(Bq, Bq, 2, 3);
    f32x2 dot = pk_add(pk_add(pk_mul(qx2, xs), pk_mul(qy2, ys)), pk_mul(qz2, zs));
    f32x2 s2  = pk_add(qw2, ws);
    f32x2 t2  = pk_add(dot, dot);
    float d2lo = __fsub_rn(s2.x, t2.x);
    float d2hi = __fsub_rn(s2.y, t2.y);
    if (c == qc) {                            // self-exclusion (wave-uniform branch)
      bool lo = qr < 16;
      int  tl = lo ? qr : qr - 16;
      if (l16 == tl) { if (lo) d2lo = 3.4e38f; else d2hi = 3.4e38f; }
    }
    half_pass(d2lo, c * 32);
    half_pass(d2hi, c * 32 + 16);
  }

  // lane = g*16 + l16 -> query 4wv+g entry l16 -> fully coalesced wave store
  idxout[(size_t)wv * 64 + lane] = lidx;
}

// ---------------- PointTransformerConv: one wave per point, fused output stats ----------------
// r5 grid (1024 blocks, 4 waves/SIMD). Neighbor indices loaded upfront (4x int4) and the
// 17-iteration loop fully unrolled with compile-time-constant jl[] indexing -> the scheduler
// can hoist/interleave the 34 S/V gathers across iterations (software pipelining) instead of
// serializing load->softmax-chain->load. __launch_bounds__(256,4) caps VGPR at 128 so the
// unroll cannot drop occupancy below r5's 4 waves/SIMD. Per-iteration FP op order unchanged.
__global__ __launch_bounds__(256, 4) void k_conv(const float* __restrict__ V, const float* __restrict__ S,
    const float* __restrict__ D, const float* __restrict__ pts, const int* __restrict__ idx,
    const float* __restrict__ pw, const float* __restrict__ pbv, float* __restrict__ Y,
    float* __restrict__ gsum, float* __restrict__ gss)
{
  int tid = threadIdx.x;
  int lane = tid & 63;
  int wid  = (blockIdx.x * 256 + tid) >> 6;  // 4096 waves
  int c0 = lane * 2;
  float2 w0  = *(const float2*)(pw + c0);
  float2 w1  = *(const float2*)(pw + 128 + c0);
  float2 w2  = *(const float2*)(pw + 256 + c0);
  float2 pb2 = *(const float2*)(pbv + c0);
  float st0 = 0.f, st1 = 0.f, sq0 = 0.f, sq1 = 0.f;
  for (int p = wid; p < PP; p += 4096) {
    int b = p >> 13, self = p & (NN - 1);
    const float* pbase = pts + (size_t)b * NN * 3;
    float pix = pbase[self*3+0], piy = pbase[self*3+1], piz = pbase[self*3+2];
    float2 di = *(const float2*)(D + (size_t)p*128 + c0);
    // neighbor list upfront: 4 x int4 (wave-uniform 64B) + self appended
    const int4* ip = (const int4*)(idx + p * KNN);
    int4 i0 = ip[0], i1 = ip[1], i2 = ip[2], i3 = ip[3];
    int jl[17] = { i0.x, i0.y, i0.z, i0.w,  i1.x, i1.y, i1.z, i1.w,
                   i2.x, i2.y, i2.z, i2.w,  i3.x, i3.y, i3.z, i3.w,  self };
    float m0 = -3.4e38f, m1 = -3.4e38f, l0 = 0.f, l1 = 0.f, a0 = 0.f, a1 = 0.f;
    #pragma unroll
    for (int t = 0; t < 17; ++t) {         // 16 kNN + self loop (appended last, as in reference)
      int j = jl[t];
      float dx = pix - pbase[j*3+0];
      float dy = piy - pbase[j*3+1];
      float dz = piz - pbase[j*3+2];
      size_t off = ((size_t)b * NN + j) * 128 + c0;
      float2 sj = *(const float2*)(S + off);
      float2 vj = *(const float2*)(V + off);
      float de0 = fmaf(dz, w2.x, fmaf(dy, w1.x, fmaf(dx, w0.x, pb2.x)));
      float de1 = fmaf(dz, w2.y, fmaf(dy, w1.y, fmaf(dx, w0.y, pb2.y)));
      float g0 = di.x - sj.x + de0;
      float g1 = di.y - sj.y + de1;
      float mn0 = fmaxf(m0, g0), mn1 = fmaxf(m1, g1);
      float cr0 = __expf(m0 - mn0), cr1 = __expf(m1 - mn1);
      float e0  = __expf(g0 - mn0), e1  = __expf(g1 - mn1);
      l0 = fmaf(l0, cr0, e0);
      l1 = fmaf(l1, cr1, e1);
      a0 = fmaf(a0, cr0, e0 * (vj.x + de0));
      a1 = fmaf(a1, cr1, e1 * (vj.y + de1));
      m0 = mn0; m1 = mn1;
    }
    float2 o; o.x = a0 / l0; o.y = a1 / l1;
    *(float2*)(Y + (size_t)p*128 + c0) = o;
    st0 += o.x; st1 += o.y;
    sq0 = fmaf(o.x, o.x, sq0); sq1 = fmaf(o.y, o.y, sq1);
  }
  __shared__ float cs[4][128], cq[4][128];
  int w = tid >> 6;
  cs[w][c0] = st0; cs[w][c0+1] = st1;
  cq[w][c0] = sq0; cq[w][c0+1] = sq1;
  __syncthreads();
  if (tid < 128) {
    float a  = cs[0][tid] + cs[1][tid] + cs[2][tid] + cs[3][tid];
    float b2 = cq[0][tid] + cq[1][tid] + cq[2][tid] + cq[3][tid];
    atomicAdd(gsum + tid, a);
    atomicAdd(gss  + tid, b2);
  }
}

// ---------------- decoder head: logits = relu(bn(t)) @ dec_w2 + dec_b2, inline BN ----------
__global__ __launch_bounds__(256) void k_dec2(const float* __restrict__ T,
    const float* __restrict__ gsumI, const float* __restrict__ gssI,
    const float* __restrict__ gamma, const float* __restrict__ beta,
    const float* __restrict__ W, const float* __restrict__ bias, float* __restrict__ out)
{
  __shared__ float xs[64][132];   // row stride 132 floats -> 16B-aligned float4 rows
  __shared__ float wt[13][128];
  __shared__ float scs[128], shs[128];
  int tid = threadIdx.x;
  int pb = blockIdx.x * 64;
  if (tid < 128) {                // inline BN finalize
    float mean = gsumI[tid] * (1.0f / PP);
    float var  = gssI[tid] * (1.0f / PP) - mean * mean;
    float s = gamma[tid] / sqrtf(var + 1e-5f);
    scs[tid] = s;
    shs[tid] = beta[tid] - mean * s;
  }
  __syncthreads();
  for (int i = tid; i < 13 * 128; i += 256) {
    int cls = i >> 7, k = i & 127;
    wt[cls][k] = W[k*13 + cls];
  }
  for (int i = tid; i < 64 * 32; i += 256) {
    int p = i >> 5, k = (i & 31) * 4;
    float4 v = *(const float4*)(T + (size_t)(pb + p)*128 + k);
    v.x = fmaxf(fmaf(v.x, scs[k+0], shs[k+0]), 0.f);
    v.y = fmaxf(fmaf(v.y, scs[k+1], shs[k+1]), 0.f);
    v.z = fmaxf(fmaf(v.z, scs[k+2], shs[k+2]), 0.f);
    v.w = fmaxf(fmaf(v.w, scs[k+3], shs[k+3]), 0.f);
    xs[p][k+0] = v.x; xs[p][k+1] = v.y; xs[p][k+2] = v.z; xs[p][k+3] = v.w;
  }
  __syncthreads();
  for (int o = tid; o < 64 * 13; o += 256) {
    int p = o / 13, cls = o - p * 13;
    float acc = bias[cls];
    const float4* xr = (const float4*)&xs[p][0];
    const float4* wr = (const float4*)&wt[cls][0];
    #pragma unroll 8
    for (int k4 = 0; k4 < 32; ++k4) {
      float4 a = xr[k4], w = wr[k4];
      acc = fmaf(a.x, w.x, acc);
      acc = fmaf(a.y, w.y, acc);
      acc = fmaf(a.z, w.z, acc);
      acc = fmaf(a.w, w.w, acc);
    }
    out[(size_t)(pb + p)*13 + cls] = acc;
  }
}

extern "C" void kernel_launch(void* const* d_in, const int* in_sizes, int n_in,
                              void* d_out, int out_size, void* d_ws, size_t ws_size,
                              hipStream_t stream)
{
  const float* pts      = (const float*)d_in[0];
  const float* embed_w1 = (const float*)d_in[1];
  const float* embed_b1 = (const float*)d_in[2];
  const float* bn1_g    = (const float*)d_in[3];
  const float* bn1_b    = (const float*)d_in[4];
  const float* embed_w2 = (const float*)d_in[5];
  const float* embed_b2 = (const float*)d_in[6];
  const float* bne_g    = (const float*)d_in[7];
  const float* bne_b    = (const float*)d_in[8];
  const float* l0_lin   = (const float*)d_in[9];
  const float* l0_src   = (const float*)d_in[10];
  const float* l0_dst   = (const float*)d_in[11];
  const float* l0_pos_w = (const float*)d_in[12];
  const float* l0_pos_b = (const float*)d_in[13];
  const float* l0_bn_g  = (const float*)d_in[14];
  const float* l0_bn_b  = (const float*)d_in[15];
  const float* l1_lin   = (const float*)d_in[16];
  const float* l1_src   = (const float*)d_in[17];
  const float* l1_dst   = (const float*)d_in[18];
  const float* l1_pos_w = (const float*)d_in[19];
  const float* l1_pos_b = (const float*)d_in[20];
  const float* l1_bn_g  = (const float*)d_in[21];
  const float* l1_bn_b  = (const float*)d_in[22];
  const float* dec_w1   = (const float*)d_in[23];
  const float* dec_b1   = (const float*)d_in[24];
  const float* dec_bn_g = (const float*)d_in[25];
  const float* dec_bn_b = (const float*)d_in[26];
  const float* dec_w2   = (const float*)d_in[27];
  const float* dec_b2   = (const float*)d_in[28];

  char* ws = (char*)d_ws;
  const size_t MB = 1024 * 1024;
  float* h1  = (float*)(ws + 0);          // 8 MB  [P,64]
  float* h2  = (float*)(ws + 8*MB);       // 8 MB  [P,64]
  int*   idx = (int*)  (ws + 16*MB);      // 2 MB  [P,16]
  float* v0  = (float*)(ws + 18*MB);      // 16 MB [P,128]  (reused for layer1)
  float* s0  = (float*)(ws + 34*MB);      // 16 MB
  float* d0  = (float*)(ws + 50*MB);      // 16 MB
  float* y0  = (float*)(ws + 66*MB);      // 16 MB
  float* y1  = (float*)(ws + 82*MB);      // 16 MB
  float* tt  = (float*)(ws + 0);          // 16 MB overlay on h1/h2 (dead by then)
  float* pairs8 = (float*)(ws + 18*MB);   // 512 KB overlay on v0 (dead once layer-0 proj runs)
  float* st  = (float*)(ws + 98*MB);      // 8 KB stats
  float *sum1=st+0,    *ss1=st+64;
  float *sum2=st+256,  *ss2=st+320;
  float *sum3=st+512,  *ss3=st+640;
  float *sum4=st+1024, *ss4=st+1152;
  float *sum5=st+1536, *ss5=st+1664;

  hipMemsetAsync(st, 0, 2048 * sizeof(float), stream);

  // kNN graph (runs first; pairs8 overlays v0, which is only written after k_knn completes)
  k_prep<<<64, 256, 0, stream>>>(pts, pairs8);
  k_knn<<<2048, 256, 0, stream>>>(pairs8, idx);   // 8192 waves x 4 queries

  // embedding MLP (stats fused into producers; BN finalize inlined in consumers)
  k_embed1<<<128, 256, 0, stream>>>(pts, embed_w1, embed_b1, h1, sum1, ss1);
  k_proj<64,64,true><<<dim3(512,1), 256, 0, stream>>>(h1, sum1, ss1, bn1_g, bn1_b,
      embed_w2, embed_w2, embed_w2, embed_b2, embed_b2, embed_b2, h2, h2, h2, sum2, ss2);

  // layer 0
  k_proj<64,128,false><<<dim3(512,3), 256, 0, stream>>>(h2, sum2, ss2, bne_g, bne_b,
      l0_lin, l0_src, l0_dst, nullptr, nullptr, nullptr, v0, s0, d0, nullptr, nullptr);
  k_conv<<<1024, 256, 0, stream>>>(v0, s0, d0, pts, idx, l0_pos_w, l0_pos_b, y0, sum3, ss3);

  // layer 1
  k_proj<128,128,false><<<dim3(512,3), 256, 0, stream>>>(y0, sum3, ss3, l0_bn_g, l0_bn_b,
      l1_lin, l1_src, l1_dst, nullptr, nullptr, nullptr, v0, s0, d0, nullptr, nullptr);
  k_conv<<<1024, 256, 0, stream>>>(v0, s0, d0, pts, idx, l1_pos_w, l1_pos_b, y1, sum4, ss4);

  // decoder
  k_proj<128,128,true><<<dim3(512,1), 256, 0, stream>>>(y1, sum4, ss4, l1_bn_g, l1_bn_b,
      dec_w1, dec_w1, dec_w1, dec_b1, dec_b1, dec_b1, tt, tt, tt, sum5, ss5);
  k_dec2<<<512, 256, 0, stream>>>(tt, sum5, ss5, dec_bn_g, dec_bn_b, dec_w2, dec_b2, (float*)d_out);
}

// Round 9
// 663.863 us; speedup vs baseline: 1.0311x; 1.0311x over previous
//
#include <hip/hip_runtime.h>
#include <math.h>

#define BB 4
#define NN 8192
#define PP 32768
#define KNN 16

typedef float f32x2 __attribute__((ext_vector_type(2)));
typedef float f32x4 __attribute__((ext_vector_type(4)));

__device__ __forceinline__ f32x2 pk_mul(f32x2 a, f32x2 b) {
  f32x2 d; asm("v_pk_mul_f32 %0, %1, %2" : "=v"(d) : "v"(a), "v"(b)); return d;
}
__device__ __forceinline__ f32x2 pk_add(f32x2 a, f32x2 b) {
  f32x2 d; asm("v_pk_add_f32 %0, %1, %2" : "=v"(d) : "v"(a), "v"(b)); return d;
}

// ---------------- embed1: h1 = pts @ w1 + b1  [P,64], fused per-channel stats ----------------
__global__ __launch_bounds__(256) void k_embed1(const float* __restrict__ pts,
    const float* __restrict__ w1, const float* __restrict__ b1, float* __restrict__ h1,
    float* __restrict__ gsum, float* __restrict__ gss)
{
  int tid = threadIdx.x;
  int c = tid & 63, g = tid >> 6;
  float wx = w1[c], wy = w1[64 + c], wz = w1[128 + c], bc = b1[c];
  int base = blockIdx.x * 256;
  float s = 0.f, ss = 0.f;
  #pragma unroll 4
  for (int i = 0; i < 64; ++i) {
    int p = base + g + i * 4;
    float px = pts[p*3+0], py = pts[p*3+1], pz = pts[p*3+2];
    float h = fmaf(pz, wz, fmaf(py, wy, fmaf(px, wx, bc)));
    h1[(size_t)p*64 + c] = h;
    s += h; ss = fmaf(h, h, ss);
  }
  __shared__ float ls[256], lq[256];
  ls[tid] = s; lq[tid] = ss;
  __syncthreads();
  if (tid < 64) {
    float a  = ls[tid] + ls[tid+64] + ls[tid+128] + ls[tid+192];
    float b2 = lq[tid] + lq[tid+64] + lq[tid+128] + lq[tid+192];
    atomicAdd(gsum + tid, a);
    atomicAdd(gss  + tid, b2);
  }
}

// ---------------- prep for kNN: pair-transposed layout, 16-slot chunks ----------------
__global__ __launch_bounds__(256) void k_prep(const float* __restrict__ pts, float* __restrict__ pp)
{
  int t = blockIdx.x * 256 + threadIdx.x;    // 16384 pair slots
  int b = t >> 12, m = t & 4095;
  int c = m >> 4, l = m & 15;
  int jl = b * NN + c * 32 + l;
  int jh = jl + 16;
  float xl = pts[jl*3+0], yl = pts[jl*3+1], zl = pts[jl*3+2];
  float xh = pts[jh*3+0], yh = pts[jh*3+1], zh = pts[jh*3+2];
  float wl = __fadd_rn(__fadd_rn(__fmul_rn(xl,xl), __fmul_rn(yl,yl)), __fmul_rn(zl,zl));
  float wh = __fadd_rn(__fadd_rn(__fmul_rn(xh,xh), __fmul_rn(yh,yh)), __fmul_rn(zh,zh));
  float* o = pp + (size_t)t * 8;
  *(float4*)(o + 0) = make_float4(xl, xh, yl, yh);
  *(float4*)(o + 4) = make_float4(zl, zh, wl, wh);
}

// ---------------- generic projection: out = relu(bn(in)) @ W (+bias), fused stats ----------
// IL: blockIdx.y 0/1 (V=lin, S=src) store interleaved into O0=SV[P][256] as channel-pair
// quads [v0 v1 s0 s1] (4x float2, same bytes); y==2 (D=dst) stays dense in O2.
template<int K, int COUT, bool STATS, bool IL>
__global__ __launch_bounds__(256) void k_proj(const float* __restrict__ in,
    const float* __restrict__ gsumI, const float* __restrict__ gssI,
    const float* __restrict__ gamma, const float* __restrict__ beta,
    const float* __restrict__ W0, const float* __restrict__ W1, const float* __restrict__ W2,
    const float* __restrict__ B0, const float* __restrict__ B1, const float* __restrict__ B2,
    float* __restrict__ O0, float* __restrict__ O1, float* __restrict__ O2,
    float* __restrict__ gsumO, float* __restrict__ gssO)
{
  constexpr int PTS = 64;
  constexpr int CW = 8;
  constexpr int CG = COUT / CW;        // channel groups: 8 (COUT=64) or 16 (COUT=128)
  constexpr int PW = PTS * CG / 256;   // points per thread: 2 or 4
  const float* W  = (blockIdx.y == 0) ? W0 : (blockIdx.y == 1) ? W1 : W2;
  const float* Bb = (blockIdx.y == 0) ? B0 : (blockIdx.y == 1) ? B1 : B2;
  float*       O  = (blockIdx.y == 0) ? O0 : (blockIdx.y == 1) ? O1 : O2;
  __shared__ float xs[PTS][K + 1];
  __shared__ float scs[K], shs[K];
  int tid = threadIdx.x;
  if (tid < K) {                        // inline BN finalize (replaces k_finalize kernel)
    float mean = gsumI[tid] * (1.0f / PP);
    float var  = gssI[tid] * (1.0f / PP) - mean * mean;
    float s = gamma[tid] / sqrtf(var + 1e-5f);
    scs[tid] = s;
    shs[tid] = beta[tid] - mean * s;
  }
  __syncthreads();
  int pbase = blockIdx.x * PTS;
  constexpr int T4 = PTS * K / 4;
  for (int i = tid; i < T4; i += 256) {
    int p = i / (K/4), k = (i % (K/4)) * 4;
    float4 v = *(const float4*)(in + (size_t)(pbase + p)*K + k);
    v.x = fmaxf(fmaf(v.x, scs[k+0], shs[k+0]), 0.f);
    v.y = fmaxf(fmaf(v.y, scs[k+1], shs[k+1]), 0.f);
    v.z = fmaxf(fmaf(v.z, scs[k+2], shs[k+2]), 0.f);
    v.w = fmaxf(fmaf(v.w, scs[k+3], shs[k+3]), 0.f);
    xs[p][k+0] = v.x; xs[p][k+1] = v.y; xs[p][k+2] = v.z; xs[p][k+3] = v.w;
  }
  __syncthreads();
  int cg = tid % CG, pg = tid / CG;
  int c0 = cg * CW, p0 = pg * PW;
  float acc[PW][CW];
  #pragma unroll
  for (int i = 0; i < PW; ++i) {
    #pragma unroll
    for (int j = 0; j < CW; ++j) acc[i][j] = 0.f;
  }
  #pragma unroll 4
  for (int k = 0; k < K; ++k) {
    float4 wa = *(const float4*)(W + (size_t)k*COUT + c0);
    float4 wb = *(const float4*)(W + (size_t)k*COUT + c0 + 4);
    #pragma unroll
    for (int i = 0; i < PW; ++i) {
      float x = xs[p0 + i][k];
      acc[i][0] = fmaf(x, wa.x, acc[i][0]);
      acc[i][1] = fmaf(x, wa.y, acc[i][1]);
      acc[i][2] = fmaf(x, wa.z, acc[i][2]);
      acc[i][3] = fmaf(x, wa.w, acc[i][3]);
      acc[i][4] = fmaf(x, wb.x, acc[i][4]);
      acc[i][5] = fmaf(x, wb.y, acc[i][5]);
      acc[i][6] = fmaf(x, wb.z, acc[i][6]);
      acc[i][7] = fmaf(x, wb.w, acc[i][7]);
    }
  }
  float bj[CW];
  #pragma unroll
  for (int j = 0; j < CW; ++j) bj[j] = Bb ? Bb[c0 + j] : 0.f;
  float sj[CW], qj[CW];
  #pragma unroll
  for (int j = 0; j < CW; ++j) { sj[j] = 0.f; qj[j] = 0.f; }
  #pragma unroll
  for (int i = 0; i < PW; ++i) {
    float o0 = acc[i][0]+bj[0], o1 = acc[i][1]+bj[1], o2 = acc[i][2]+bj[2], o3 = acc[i][3]+bj[3];
    float o4 = acc[i][4]+bj[4], o5 = acc[i][5]+bj[5], o6 = acc[i][6]+bj[6], o7 = acc[i][7]+bj[7];
    if (IL && blockIdx.y != 2) {
      float* op = O0 + (size_t)(pbase + p0 + i)*256 + c0*2 + (blockIdx.y ? 2 : 0);
      *(float2*)(op +  0) = make_float2(o0, o1);
      *(float2*)(op +  4) = make_float2(o2, o3);
      *(float2*)(op +  8) = make_float2(o4, o5);
      *(float2*)(op + 12) = make_float2(o6, o7);
    } else {
      float* op = O + (size_t)(pbase + p0 + i)*COUT + c0;
      *(float4*)(op)     = make_float4(o0, o1, o2, o3);
      *(float4*)(op + 4) = make_float4(o4, o5, o6, o7);
    }
    if (STATS) {
      sj[0]+=o0; sj[1]+=o1; sj[2]+=o2; sj[3]+=o3; sj[4]+=o4; sj[5]+=o5; sj[6]+=o6; sj[7]+=o7;
      qj[0]=fmaf(o0,o0,qj[0]); qj[1]=fmaf(o1,o1,qj[1]); qj[2]=fmaf(o2,o2,qj[2]); qj[3]=fmaf(o3,o3,qj[3]);
      qj[4]=fmaf(o4,o4,qj[4]); qj[5]=fmaf(o5,o5,qj[5]); qj[6]=fmaf(o6,o6,qj[6]); qj[7]=fmaf(o7,o7,qj[7]);
    }
  }
  if (STATS) {
    #pragma unroll
    for (int off = CG; off < 64; off <<= 1) {
      #pragma unroll
      for (int j = 0; j < CW; ++j) {
        sj[j] += __shfl_xor(sj[j], off);
        qj[j] += __shfl_xor(qj[j], off);
      }
    }
    __shared__ float ws[4][COUT], wq[4][COUT];
    int wid = tid >> 6, lane = tid & 63;
    if (lane < CG) {
      #pragma unroll
      for (int j = 0; j < CW; ++j) { ws[wid][lane*CW+j] = sj[j]; wq[wid][lane*CW+j] = qj[j]; }
    }
    __syncthreads();
    if (tid < COUT) {
      float a  = ws[0][tid] + ws[1][tid] + ws[2][tid] + ws[3][tid];
      float b2 = wq[0][tid] + wq[1][tid] + wq[2][tid] + wq[3][tid];
      atomicAdd(gsumO + tid, a);
      atomicAdd(gssO  + tid, b2);
    }
  }
}

// ---------------- kNN-16 v3 (measured best): 4 queries/wave, serial insert ----------------
__global__ __launch_bounds__(256, 8) void k_knn(const float* __restrict__ pp, int* __restrict__ idxout)
{
  int tid = threadIdx.x;
  int lane = tid & 63;
  int l16 = lane & 15;
  int g64 = lane & 48;                       // group base lane (0,16,32,48)
  int wv = (blockIdx.x * 256 + tid) >> 6;    // 8192 waves
  int b  = wv >> 11;                         // 2048 waves per batch
  int qbase = (wv * 4) & (NN - 1);
  int qc = qbase >> 5;                       // wave-uniform chunk containing all 4 queries
  int qr = (qbase & 31) + (lane >> 4);       // query position within chunk (per group)
  const float* pb = pp + (size_t)b * (NN * 4);

  // query coords (broadcast load within each group)
  float qx, qy, qz, qw;
  {
    int qslot = qc * 16 + (qr & 15);
    int qh = (qr >> 4) & 1;
    const float* qp = pb + (size_t)qslot * 8 + qh;
    qx = qp[0]; qy = qp[2]; qz = qp[4]; qw = qp[6];
  }
  f32x2 qx2; qx2.x = qx; qx2.y = qx;
  f32x2 qy2; qy2.x = qy; qy2.y = qy;
  f32x2 qz2; qz2.x = qz; qz2.y = qz;
  f32x2 qw2; qw2.x = qw; qw2.y = qw;

  int addr_push = (lane + 1) << 2;           // ds_permute: push lval to lane+1 (l16==0 ignores pv)
  int addr_tau  = (g64 + 15) << 2;           // ds_bpermute: read own group's list[15]

  float lval = 3.4e38f;  // list entry held by this lane (ascending in l16 within group)
  int   lidx = 0;
  float tau  = 3.4e38f;  // per-group 16th-best (replicated in group's lanes)

  // drain one half-chunk's candidates into the 4 group lists (parallel across groups)
  auto half_pass = [&](float d2, int jbase) {
    unsigned long long bal = __ballot(d2 < tau);
    if (bal) {
      unsigned slice = (unsigned)(bal >> g64) & 0xffffu;
      while (__ballot(slice != 0)) {
        bool live = slice != 0;
        int src = __ffs((int)slice) - 1;     // -1 when this group's slice is empty
        slice &= slice - 1;
        int ab = (g64 + (src & 15)) << 2;
        float v = __uint_as_float(__builtin_amdgcn_ds_bpermute(ab, __float_as_uint(d2)));
        if (!live) v = 3.4e38f;              // empty group -> no-op insert
        int jc = jbase + src;
        float pv = __uint_as_float(__builtin_amdgcn_ds_permute(addr_push, __float_as_uint(lval)));
        int   pi = __builtin_amdgcn_ds_permute(addr_push, lidx);
        bool atpos = (l16 == 0) || (pv <= v);
        if (lval > v) {
          lval = atpos ? v  : pv;
          lidx = atpos ? jc : pi;
        }
      }
      tau = __uint_as_float(__builtin_amdgcn_ds_bpermute(addr_tau, __float_as_uint(lval)));
    }
  };

  const float* cp = pb + (size_t)l16 * 8;

  // ---- chunk 0 (peeled): lo half seeds via bitonic sort, hi half via normal insert ----
  {
    f32x4 A  = *(const f32x4*)(cp + 0);
    f32x4 Bq = *(const f32x4*)(cp + 4);
    cp += 128;
    f32x2 xs = __builtin_shufflevector(A, A, 0, 1);
    f32x2 ys = __builtin_shufflevector(A, A, 2, 3);
    f32x2 zs = __builtin_shufflevector(Bq, Bq, 0, 1);
    f32x2 ws = __builtin_shufflevector(Bq, Bq, 2, 3);
    f32x2 dot = pk_add(pk_add(pk_mul(qx2, xs), pk_mul(qy2, ys)), pk_mul(qz2, zs));
    f32x2 s2  = pk_add(qw2, ws);
    f32x2 t2  = pk_add(dot, dot);
    float d2lo = __fsub_rn(s2.x, t2.x);
    float d2hi = __fsub_rn(s2.y, t2.y);
    if (qc == 0) {                            // self-exclusion (wave-uniform branch)
      bool lo = qr < 16;
      int  tl = lo ? qr : qr - 16;
      if (l16 == tl) { if (lo) d2lo = 3.4e38f; else d2hi = 3.4e38f; }
    }
    // 16-lane bitonic sort of (d2lo, j=l16), ascending by (d2, j) within each group
    float v = d2lo; int ix = l16;
    #pragma unroll
    for (int k = 2; k <= 16; k <<= 1) {
      #pragma unroll
      for (int j = k >> 1; j >= 1; j >>= 1) {
        float ov = __shfl_xor(v, j, 16);
        int   oi = __shfl_xor(ix, j, 16);
        bool up    = (l16 & k) == 0;
        bool lower = (l16 & j) == 0;
        bool lt = (ov < v) || (ov == v && oi < ix);
        if ((up == lower) ? lt : !lt) { v = ov; ix = oi; }
      }
    }
    lval = v; lidx = ix;
    tau = __uint_as_float(__builtin_amdgcn_ds_bpermute(addr_tau, __float_as_uint(lval)));
    half_pass(d2hi, 16);
  }

  // ---- chunks 1..255 ----
  for (int c = 1; c < 256; ++c) {
    f32x4 A  = *(const f32x4*)(cp + 0);
    f32x4 Bq = *(const f32x4*)(cp + 4);
    cp += 128;
    f32x2 xs = __builtin_shufflevector(A, A, 0, 1);
    f32x2 ys = __builtin_shufflevector(A, A, 2, 3);
    f32x2 zs = __builtin_shufflevector(Bq, Bq, 0, 1);
    f32x2 ws = __builtin_shufflevector(Bq, Bq, 2, 3);
    f32x2 dot = pk_add(pk_add(pk_mul(qx2, xs), pk_mul(qy2, ys)), pk_mul(qz2, zs));
    f32x2 s2  = pk_add(qw2, ws);
    f32x2 t2  = pk_add(dot, dot);
    float d2lo = __fsub_rn(s2.x, t2.x);
    float d2hi = __fsub_rn(s2.y, t2.y);
    if (c == qc) {                            // self-exclusion (wave-uniform branch)
      bool lo = qr < 16;
      int  tl = lo ? qr : qr - 16;
      if (l16 == tl) { if (lo) d2lo = 3.4e38f; else d2hi = 3.4e38f; }
    }
    half_pass(d2lo, c * 32);
    half_pass(d2hi, c * 32 + 16);
  }

  // lane = g*16 + l16 -> query 4wv+g entry l16 -> fully coalesced wave store
  idxout[(size_t)wv * 64 + lane] = lidx;
}

// ---------------- PointTransformerConv: one wave per point, fused output stats ----------------
// r5 structure (1024 blocks, rolled loop). S and V are interleaved in SV[P][256] as
// channel-pair quads [v0 v1 s0 s1] -> ONE 16B gather per neighbor per lane instead of two
// 8B gathers to two distant arrays (half the VMEM instructions / gather rounds on the hot
// path). FP math and iteration order unchanged -> bit-identical output.
__global__ __launch_bounds__(256) void k_conv(const float* __restrict__ SV,
    const float* __restrict__ D, const float* __restrict__ pts, const int* __restrict__ idx,
    const float* __restrict__ pw, const float* __restrict__ pbv, float* __restrict__ Y,
    float* __restrict__ gsum, float* __restrict__ gss)
{
  int tid = threadIdx.x;
  int lane = tid & 63;
  int wid  = (blockIdx.x * 256 + tid) >> 6;  // 4096 waves
  int c0 = lane * 2;
  float2 w0  = *(const float2*)(pw + c0);
  float2 w1  = *(const float2*)(pw + 128 + c0);
  float2 w2  = *(const float2*)(pw + 256 + c0);
  float2 pb2 = *(const float2*)(pbv + c0);
  float st0 = 0.f, st1 = 0.f, sq0 = 0.f, sq1 = 0.f;
  for (int p = wid; p < PP; p += 4096) {
    int b = p >> 13, self = p & (NN - 1);
    const float* pbase = pts + (size_t)b * NN * 3;
    float pix = pbase[self*3+0], piy = pbase[self*3+1], piz = pbase[self*3+2];
    float2 di = *(const float2*)(D + (size_t)p*128 + c0);
    float m0 = -3.4e38f, m1 = -3.4e38f, l0 = 0.f, l1 = 0.f, a0 = 0.f, a1 = 0.f;
    for (int t = 0; t < 17; ++t) {         // 16 kNN + self loop (appended last, as in reference)
      int j = (t < 16) ? idx[p*KNN + t] : self;
      float dx = pix - pbase[j*3+0];
      float dy = piy - pbase[j*3+1];
      float dz = piz - pbase[j*3+2];
      size_t off = ((size_t)b * NN + j) * 256 + c0 * 2;
      float4 sv = *(const float4*)(SV + off);       // {v0, v1, s0, s1}
      float2 vj = make_float2(sv.x, sv.y);
      float2 sj = make_float2(sv.z, sv.w);
      float de0 = fmaf(dz, w2.x, fmaf(dy, w1.x, fmaf(dx, w0.x, pb2.x)));
      float de1 = fmaf(dz, w2.y, fmaf(dy, w1.y, fmaf(dx, w0.y, pb2.y)));
      float g0 = di.x - sj.x + de0;
      float g1 = di.y - sj.y + de1;
      float mn0 = fmaxf(m0, g0), mn1 = fmaxf(m1, g1);
      float cr0 = __expf(m0 - mn0), cr1 = __expf(m1 - mn1);
      float e0  = __expf(g0 - mn0), e1  = __expf(g1 - mn1);
      l0 = fmaf(l0, cr0, e0);
      l1 = fmaf(l1, cr1, e1);
      a0 = fmaf(a0, cr0, e0 * (vj.x + de0));
      a1 = fmaf(a1, cr1, e1 * (vj.y + de1));
      m0 = mn0; m1 = mn1;
    }
    float2 o; o.x = a0 / l0; o.y = a1 / l1;
    *(float2*)(Y + (size_t)p*128 + c0) = o;
    st0 += o.x; st1 += o.y;
    sq0 = fmaf(o.x, o.x, sq0); sq1 = fmaf(o.y, o.y, sq1);
  }
  __shared__ float cs[4][128], cq[4][128];
  int w = tid >> 6;
  cs[w][c0] = st0; cs[w][c0+1] = st1;
  cq[w][c0] = sq0; cq[w][c0+1] = sq1;
  __syncthreads();
  if (tid < 128) {
    float a  = cs[0][tid] + cs[1][tid] + cs[2][tid] + cs[3][tid];
    float b2 = cq[0][tid] + cq[1][tid] + cq[2][tid] + cq[3][tid];
    atomicAdd(gsum + tid, a);
    atomicAdd(gss  + tid, b2);
  }
}

// ---------------- decoder head: logits = relu(bn(t)) @ dec_w2 + dec_b2, inline BN ----------
__global__ __launch_bounds__(256) void k_dec2(const float* __restrict__ T,
    const float* __restrict__ gsumI, const float* __restrict__ gssI,
    const float* __restrict__ gamma, const float* __restrict__ beta,
    const float* __restrict__ W, const float* __restrict__ bias, float* __restrict__ out)
{
  __shared__ float xs[64][132];   // row stride 132 floats -> 16B-aligned float4 rows
  __shared__ float wt[13][128];
  __shared__ float scs[128], shs[128];
  int tid = threadIdx.x;
  int pb = blockIdx.x * 64;
  if (tid < 128) {                // inline BN finalize
    float mean = gsumI[tid] * (1.0f / PP);
    float var  = gssI[tid] * (1.0f / PP) - mean * mean;
    float s = gamma[tid] / sqrtf(var + 1e-5f);
    scs[tid] = s;
    shs[tid] = beta[tid] - mean * s;
  }
  __syncthreads();
  for (int i = tid; i < 13 * 128; i += 256) {
    int cls = i >> 7, k = i & 127;
    wt[cls][k] = W[k*13 + cls];
  }
  for (int i = tid; i < 64 * 32; i += 256) {
    int p = i >> 5, k = (i & 31) * 4;
    float4 v = *(const float4*)(T + (size_t)(pb + p)*128 + k);
    v.x = fmaxf(fmaf(v.x, scs[k+0], shs[k+0]), 0.f);
    v.y = fmaxf(fmaf(v.y, scs[k+1], shs[k+1]), 0.f);
    v.z = fmaxf(fmaf(v.z, scs[k+2], shs[k+2]), 0.f);
    v.w = fmaxf(fmaf(v.w, scs[k+3], shs[k+3]), 0.f);
    xs[p][k+0] = v.x; xs[p][k+1] = v.y; xs[p][k+2] = v.z; xs[p][k+3] = v.w;
  }
  __syncthreads();
  for (int o = tid; o < 64 * 13; o += 256) {
    int p = o / 13, cls = o - p * 13;
    float acc = bias[cls];
    const float4* xr = (const float4*)&xs[p][0];
    const float4* wr = (const float4*)&wt[cls][0];
    #pragma unroll 8
    for (int k4 = 0; k4 < 32; ++k4) {
      float4 a = xr[k4], w = wr[k4];
      acc = fmaf(a.x, w.x, acc);
      acc = fmaf(a.y, w.y, acc);
      acc = fmaf(a.z, w.z, acc);
      acc = fmaf(a.w, w.w, acc);
    }
    out[(size_t)(pb + p)*13 + cls] = acc;
  }
}

extern "C" void kernel_launch(void* const* d_in, const int* in_sizes, int n_in,
                              void* d_out, int out_size, void* d_ws, size_t ws_size,
                              hipStream_t stream)
{
  const float* pts      = (const float*)d_in[0];
  const float* embed_w1 = (const float*)d_in[1];
  const float* embed_b1 = (const float*)d_in[2];
  const float* bn1_g    = (const float*)d_in[3];
  const float* bn1_b    = (const float*)d_in[4];
  const float* embed_w2 = (const float*)d_in[5];
  const float* embed_b2 = (const float*)d_in[6];
  const float* bne_g    = (const float*)d_in[7];
  const float* bne_b    = (const float*)d_in[8];
  const float* l0_lin   = (const float*)d_in[9];
  const float* l0_src   = (const float*)d_in[10];
  const float* l0_dst   = (const float*)d_in[11];
  const float* l0_pos_w = (const float*)d_in[12];
  const float* l0_pos_b = (const float*)d_in[13];
  const float* l0_bn_g  = (const float*)d_in[14];
  const float* l0_bn_b  = (const float*)d_in[15];
  const float* l1_lin   = (const float*)d_in[16];
  const float* l1_src   = (const float*)d_in[17];
  const float* l1_dst   = (const float*)d_in[18];
  const float* l1_pos_w = (const float*)d_in[19];
  const float* l1_pos_b = (const float*)d_in[20];
  const float* l1_bn_g  = (const float*)d_in[21];
  const float* l1_bn_b  = (const float*)d_in[22];
  const float* dec_w1   = (const float*)d_in[23];
  const float* dec_b1   = (const float*)d_in[24];
  const float* dec_bn_g = (const float*)d_in[25];
  const float* dec_bn_b = (const float*)d_in[26];
  const float* dec_w2   = (const float*)d_in[27];
  const float* dec_b2   = (const float*)d_in[28];

  char* ws = (char*)d_ws;
  const size_t MB = 1024 * 1024;
  float* h1  = (float*)(ws + 0);          // 8 MB  [P,64]
  float* h2  = (float*)(ws + 8*MB);       // 8 MB  [P,64]
  int*   idx = (int*)  (ws + 16*MB);      // 2 MB  [P,16]
  float* sv  = (float*)(ws + 18*MB);      // 32 MB [P,256]  V/S interleaved (reused for layer1)
  float* d0  = (float*)(ws + 50*MB);      // 16 MB [P,128]  dst
  float* y0  = (float*)(ws + 66*MB);      // 16 MB
  float* y1  = (float*)(ws + 82*MB);      // 16 MB
  float* tt  = (float*)(ws + 0);          // 16 MB overlay on h1/h2 (dead by then)
  float* pairs8 = (float*)(ws + 18*MB);   // 512 KB overlay on sv (dead once layer-0 proj runs)
  float* st  = (float*)(ws + 98*MB);      // 8 KB stats
  float *sum1=st+0,    *ss1=st+64;
  float *sum2=st+256,  *ss2=st+320;
  float *sum3=st+512,  *ss3=st+640;
  float *sum4=st+1024, *ss4=st+1152;
  float *sum5=st+1536, *ss5=st+1664;

  hipMemsetAsync(st, 0, 2048 * sizeof(float), stream);

  // kNN graph (runs first; pairs8 overlays sv, which is only written after k_knn completes)
  k_prep<<<64, 256, 0, stream>>>(pts, pairs8);
  k_knn<<<2048, 256, 0, stream>>>(pairs8, idx);   // 8192 waves x 4 queries

  // embedding MLP (stats fused into producers; BN finalize inlined in consumers)
  k_embed1<<<128, 256, 0, stream>>>(pts, embed_w1, embed_b1, h1, sum1, ss1);
  k_proj<64,64,true,false><<<dim3(512,1), 256, 0, stream>>>(h1, sum1, ss1, bn1_g, bn1_b,
      embed_w2, embed_w2, embed_w2, embed_b2, embed_b2, embed_b2, h2, h2, h2, sum2, ss2);

  // layer 0 (lin/src interleaved into sv; dst dense in d0)
  k_proj<64,128,false,true><<<dim3(512,3), 256, 0, stream>>>(h2, sum2, ss2, bne_g, bne_b,
      l0_lin, l0_src, l0_dst, nullptr, nullptr, nullptr, sv, sv, d0, nullptr, nullptr);
  k_conv<<<1024, 256, 0, stream>>>(sv, d0, pts, idx, l0_pos_w, l0_pos_b, y0, sum3, ss3);

  // layer 1
  k_proj<128,128,false,true><<<dim3(512,3), 256, 0, stream>>>(y0, sum3, ss3, l0_bn_g, l0_bn_b,
      l1_lin, l1_src, l1_dst, nullptr, nullptr, nullptr, sv, sv, d0, nullptr, nullptr);
  k_conv<<<1024, 256, 0, stream>>>(sv, d0, pts, idx, l1_pos_w, l1_pos_b, y1, sum4, ss4);

  // decoder
  k_proj<128,128,true,false><<<dim3(512,1), 256, 0, stream>>>(y1, sum4, ss4, l1_bn_g, l1_bn_b,
      dec_w1, dec_w1, dec_w1, dec_b1, dec_b1, dec_b1, tt, tt, tt, sum5, ss5);
  k_dec2<<<512, 256, 0, stream>>>(tt, sum5, ss5, dec_bn_g, dec_bn_b, dec_w2, dec_b2, (float*)d_out);
}

// Round 10
// 617.454 us; speedup vs baseline: 1.1086x; 1.0752x over previous
//
#include <hip/hip_runtime.h>
#include <math.h>

#define BB 4
#define NN 8192
#define PP 32768
#define KNN 16

typedef float f32x2 __attribute__((ext_vector_type(2)));
typedef float f32x4 __attribute__((ext_vector_type(4)));

__device__ __forceinline__ f32x2 pk_mul(f32x2 a, f32x2 b) {
  f32x2 d; asm("v_pk_mul_f32 %0, %1, %2" : "=v"(d) : "v"(a), "v"(b)); return d;
}
__device__ __forceinline__ f32x2 pk_add(f32x2 a, f32x2 b) {
  f32x2 d; asm("v_pk_add_f32 %0, %1, %2" : "=v"(d) : "v"(a), "v"(b)); return d;
}

// ---------------- embed1: h1 = pts @ w1 + b1  [P,64], fused per-channel stats ----------------
__global__ __launch_bounds__(256) void k_embed1(const float* __restrict__ pts,
    const float* __restrict__ w1, const float* __restrict__ b1, float* __restrict__ h1,
    float* __restrict__ gsum, float* __restrict__ gss)
{
  int tid = threadIdx.x;
  int c = tid & 63, g = tid >> 6;
  float wx = w1[c], wy = w1[64 + c], wz = w1[128 + c], bc = b1[c];
  int base = blockIdx.x * 256;
  float s = 0.f, ss = 0.f;
  #pragma unroll 4
  for (int i = 0; i < 64; ++i) {
    int p = base + g + i * 4;
    float px = pts[p*3+0], py = pts[p*3+1], pz = pts[p*3+2];
    float h = fmaf(pz, wz, fmaf(py, wy, fmaf(px, wx, bc)));
    h1[(size_t)p*64 + c] = h;
    s += h; ss = fmaf(h, h, ss);
  }
  __shared__ float ls[256], lq[256];
  ls[tid] = s; lq[tid] = ss;
  __syncthreads();
  if (tid < 64) {
    float a  = ls[tid] + ls[tid+64] + ls[tid+128] + ls[tid+192];
    float b2 = lq[tid] + lq[tid+64] + lq[tid+128] + lq[tid+192];
    atomicAdd(gsum + tid, a);
    atomicAdd(gss  + tid, b2);
  }
}

// ---------------- prep for kNN: pair-transposed layout, 16-slot chunks ----------------
__global__ __launch_bounds__(256) void k_prep(const float* __restrict__ pts, float* __restrict__ pp)
{
  int t = blockIdx.x * 256 + threadIdx.x;    // 16384 pair slots
  int b = t >> 12, m = t & 4095;
  int c = m >> 4, l = m & 15;
  int jl = b * NN + c * 32 + l;
  int jh = jl + 16;
  float xl = pts[jl*3+0], yl = pts[jl*3+1], zl = pts[jl*3+2];
  float xh = pts[jh*3+0], yh = pts[jh*3+1], zh = pts[jh*3+2];
  float wl = __fadd_rn(__fadd_rn(__fmul_rn(xl,xl), __fmul_rn(yl,yl)), __fmul_rn(zl,zl));
  float wh = __fadd_rn(__fadd_rn(__fmul_rn(xh,xh), __fmul_rn(yh,yh)), __fmul_rn(zh,zh));
  float* o = pp + (size_t)t * 8;
  *(float4*)(o + 0) = make_float4(xl, xh, yl, yh);
  *(float4*)(o + 4) = make_float4(zl, zh, wl, wh);
}

// ---------------- generic projection: out = relu(bn(in)) @ W (+bias), fused stats ----------
template<int K, int COUT, bool STATS>
__global__ __launch_bounds__(256) void k_proj(const float* __restrict__ in,
    const float* __restrict__ gsumI, const float* __restrict__ gssI,
    const float* __restrict__ gamma, const float* __restrict__ beta,
    const float* __restrict__ W0, const float* __restrict__ W1, const float* __restrict__ W2,
    const float* __restrict__ B0, const float* __restrict__ B1, const float* __restrict__ B2,
    float* __restrict__ O0, float* __restrict__ O1, float* __restrict__ O2,
    float* __restrict__ gsumO, float* __restrict__ gssO)
{
  constexpr int PTS = 64;
  constexpr int CW = 8;
  constexpr int CG = COUT / CW;        // channel groups: 8 (COUT=64) or 16 (COUT=128)
  constexpr int PW = PTS * CG / 256;   // points per thread: 2 or 4
  const float* W  = (blockIdx.y == 0) ? W0 : (blockIdx.y == 1) ? W1 : W2;
  const float* Bb = (blockIdx.y == 0) ? B0 : (blockIdx.y == 1) ? B1 : B2;
  float*       O  = (blockIdx.y == 0) ? O0 : (blockIdx.y == 1) ? O1 : O2;
  __shared__ float xs[PTS][K + 1];
  __shared__ float scs[K], shs[K];
  int tid = threadIdx.x;
  if (tid < K) {                        // inline BN finalize (replaces k_finalize kernel)
    float mean = gsumI[tid] * (1.0f / PP);
    float var  = gssI[tid] * (1.0f / PP) - mean * mean;
    float s = gamma[tid] / sqrtf(var + 1e-5f);
    scs[tid] = s;
    shs[tid] = beta[tid] - mean * s;
  }
  __syncthreads();
  int pbase = blockIdx.x * PTS;
  constexpr int T4 = PTS * K / 4;
  for (int i = tid; i < T4; i += 256) {
    int p = i / (K/4), k = (i % (K/4)) * 4;
    float4 v = *(const float4*)(in + (size_t)(pbase + p)*K + k);
    v.x = fmaxf(fmaf(v.x, scs[k+0], shs[k+0]), 0.f);
    v.y = fmaxf(fmaf(v.y, scs[k+1], shs[k+1]), 0.f);
    v.z = fmaxf(fmaf(v.z, scs[k+2], shs[k+2]), 0.f);
    v.w = fmaxf(fmaf(v.w, scs[k+3], shs[k+3]), 0.f);
    xs[p][k+0] = v.x; xs[p][k+1] = v.y; xs[p][k+2] = v.z; xs[p][k+3] = v.w;
  }
  __syncthreads();
  int cg = tid % CG, pg = tid / CG;
  int c0 = cg * CW, p0 = pg * PW;
  float acc[PW][CW];
  #pragma unroll
  for (int i = 0; i < PW; ++i) {
    #pragma unroll
    for (int j = 0; j < CW; ++j) acc[i][j] = 0.f;
  }
  #pragma unroll 4
  for (int k = 0; k < K; ++k) {
    float4 wa = *(const float4*)(W + (size_t)k*COUT + c0);
    float4 wb = *(const float4*)(W + (size_t)k*COUT + c0 + 4);
    #pragma unroll
    for (int i = 0; i < PW; ++i) {
      float x = xs[p0 + i][k];
      acc[i][0] = fmaf(x, wa.x, acc[i][0]);
      acc[i][1] = fmaf(x, wa.y, acc[i][1]);
      acc[i][2] = fmaf(x, wa.z, acc[i][2]);
      acc[i][3] = fmaf(x, wa.w, acc[i][3]);
      acc[i][4] = fmaf(x, wb.x, acc[i][4]);
      acc[i][5] = fmaf(x, wb.y, acc[i][5]);
      acc[i][6] = fmaf(x, wb.z, acc[i][6]);
      acc[i][7] = fmaf(x, wb.w, acc[i][7]);
    }
  }
  float bj[CW];
  #pragma unroll
  for (int j = 0; j < CW; ++j) bj[j] = Bb ? Bb[c0 + j] : 0.f;
  float sj[CW], qj[CW];
  #pragma unroll
  for (int j = 0; j < CW; ++j) { sj[j] = 0.f; qj[j] = 0.f; }
  #pragma unroll
  for (int i = 0; i < PW; ++i) {
    float* op = O + (size_t)(pbase + p0 + i)*COUT + c0;
    float o0 = acc[i][0]+bj[0], o1 = acc[i][1]+bj[1], o2 = acc[i][2]+bj[2], o3 = acc[i][3]+bj[3];
    float o4 = acc[i][4]+bj[4], o5 = acc[i][5]+bj[5], o6 = acc[i][6]+bj[6], o7 = acc[i][7]+bj[7];
    *(float4*)(op)     = make_float4(o0, o1, o2, o3);
    *(float4*)(op + 4) = make_float4(o4, o5, o6, o7);
    if (STATS) {
      sj[0]+=o0; sj[1]+=o1; sj[2]+=o2; sj[3]+=o3; sj[4]+=o4; sj[5]+=o5; sj[6]+=o6; sj[7]+=o7;
      qj[0]=fmaf(o0,o0,qj[0]); qj[1]=fmaf(o1,o1,qj[1]); qj[2]=fmaf(o2,o2,qj[2]); qj[3]=fmaf(o3,o3,qj[3]);
      qj[4]=fmaf(o4,o4,qj[4]); qj[5]=fmaf(o5,o5,qj[5]); qj[6]=fmaf(o6,o6,qj[6]); qj[7]=fmaf(o7,o7,qj[7]);
    }
  }
  if (STATS) {
    #pragma unroll
    for (int off = CG; off < 64; off <<= 1) {
      #pragma unroll
      for (int j = 0; j < CW; ++j) {
        sj[j] += __shfl_xor(sj[j], off);
        qj[j] += __shfl_xor(qj[j], off);
      }
    }
    __shared__ float ws[4][COUT], wq[4][COUT];
    int wid = tid >> 6, lane = tid & 63;
    if (lane < CG) {
      #pragma unroll
      for (int j = 0; j < CW; ++j) { ws[wid][lane*CW+j] = sj[j]; wq[wid][lane*CW+j] = qj[j]; }
    }
    __syncthreads();
    if (tid < COUT) {
      float a  = ws[0][tid] + ws[1][tid] + ws[2][tid] + ws[3][tid];
      float b2 = wq[0][tid] + wq[1][tid] + wq[2][tid] + wq[3][tid];
      atomicAdd(gsumO + tid, a);
      atomicAdd(gssO  + tid, b2);
    }
  }
}

// ---------------- kNN-16 v3 (measured best): 4 queries/wave, serial insert ----------------
__global__ __launch_bounds__(256, 8) void k_knn(const float* __restrict__ pp, int* __restrict__ idxout)
{
  int tid = threadIdx.x;
  int lane = tid & 63;
  int l16 = lane & 15;
  int g64 = lane & 48;                       // group base lane (0,16,32,48)
  int wv = (blockIdx.x * 256 + tid) >> 6;    // 8192 waves
  int b  = wv >> 11;                         // 2048 waves per batch
  int qbase = (wv * 4) & (NN - 1);
  int qc = qbase >> 5;                       // wave-uniform chunk containing all 4 queries
  int qr = (qbase & 31) + (lane >> 4);       // query position within chunk (per group)
  const float* pb = pp + (size_t)b * (NN * 4);

  // query coords (broadcast load within each group)
  float qx, qy, qz, qw;
  {
    int qslot = qc * 16 + (qr & 15);
    int qh = (qr >> 4) & 1;
    const float* qp = pb + (size_t)qslot * 8 + qh;
    qx = qp[0]; qy = qp[2]; qz = qp[4]; qw = qp[6];
  }
  f32x2 qx2; qx2.x = qx; qx2.y = qx;
  f32x2 qy2; qy2.x = qy; qy2.y = qy;
  f32x2 qz2; qz2.x = qz; qz2.y = qz;
  f32x2 qw2; qw2.x = qw; qw2.y = qw;

  int addr_push = (lane + 1) << 2;           // ds_permute: push lval to lane+1 (l16==0 ignores pv)
  int addr_tau  = (g64 + 15) << 2;           // ds_bpermute: read own group's list[15]

  float lval = 3.4e38f;  // list entry held by this lane (ascending in l16 within group)
  int   lidx = 0;
  float tau  = 3.4e38f;  // per-group 16th-best (replicated in group's lanes)

  // drain one half-chunk's candidates into the 4 group lists (parallel across groups)
  auto half_pass = [&](float d2, int jbase) {
    unsigned long long bal = __ballot(d2 < tau);
    if (bal) {
      unsigned slice = (unsigned)(bal >> g64) & 0xffffu;
      while (__ballot(slice != 0)) {
        bool live = slice != 0;
        int src = __ffs((int)slice) - 1;     // -1 when this group's slice is empty
        slice &= slice - 1;
        int ab = (g64 + (src & 15)) << 2;
        float v = __uint_as_float(__builtin_amdgcn_ds_bpermute(ab, __float_as_uint(d2)));
        if (!live) v = 3.4e38f;              // empty group -> no-op insert
        int jc = jbase + src;
        float pv = __uint_as_float(__builtin_amdgcn_ds_permute(addr_push, __float_as_uint(lval)));
        int   pi = __builtin_amdgcn_ds_permute(addr_push, lidx);
        bool atpos = (l16 == 0) || (pv <= v);
        if (lval > v) {
          lval = atpos ? v  : pv;
          lidx = atpos ? jc : pi;
        }
      }
      tau = __uint_as_float(__builtin_amdgcn_ds_bpermute(addr_tau, __float_as_uint(lval)));
    }
  };

  const float* cp = pb + (size_t)l16 * 8;

  // ---- chunk 0 (peeled): lo half seeds via bitonic sort, hi half via normal insert ----
  {
    f32x4 A  = *(const f32x4*)(cp + 0);
    f32x4 Bq = *(const f32x4*)(cp + 4);
    cp += 128;
    f32x2 xs = __builtin_shufflevector(A, A, 0, 1);
    f32x2 ys = __builtin_shufflevector(A, A, 2, 3);
    f32x2 zs = __builtin_shufflevector(Bq, Bq, 0, 1);
    f32x2 ws = __builtin_shufflevector(Bq, Bq, 2, 3);
    f32x2 dot = pk_add(pk_add(pk_mul(qx2, xs), pk_mul(qy2, ys)), pk_mul(qz2, zs));
    f32x2 s2  = pk_add(qw2, ws);
    f32x2 t2  = pk_add(dot, dot);
    float d2lo = __fsub_rn(s2.x, t2.x);
    float d2hi = __fsub_rn(s2.y, t2.y);
    if (qc == 0) {                            // self-exclusion (wave-uniform branch)
      bool lo = qr < 16;
      int  tl = lo ? qr : qr - 16;
      if (l16 == tl) { if (lo) d2lo = 3.4e38f; else d2hi = 3.4e38f; }
    }
    // 16-lane bitonic sort of (d2lo, j=l16), ascending by (d2, j) within each group
    float v = d2lo; int ix = l16;
    #pragma unroll
    for (int k = 2; k <= 16; k <<= 1) {
      #pragma unroll
      for (int j = k >> 1; j >= 1; j >>= 1) {
        float ov = __shfl_xor(v, j, 16);
        int   oi = __shfl_xor(ix, j, 16);
        bool up    = (l16 & k) == 0;
        bool lower = (l16 & j) == 0;
        bool lt = (ov < v) || (ov == v && oi < ix);
        if ((up == lower) ? lt : !lt) { v = ov; ix = oi; }
      }
    }
    lval = v; lidx = ix;
    tau = __uint_as_float(__builtin_amdgcn_ds_bpermute(addr_tau, __float_as_uint(lval)));
    half_pass(d2hi, 16);
  }

  // ---- chunks 1..255 ----
  for (int c = 1; c < 256; ++c) {
    f32x4 A  = *(const f32x4*)(cp + 0);
    f32x4 Bq = *(const f32x4*)(cp + 4);
    cp += 128;
    f32x2 xs = __builtin_shufflevector(A, A, 0, 1);
    f32x2 ys = __builtin_shufflevector(A, A, 2, 3);
    f32x2 zs = __builtin_shufflevector(Bq, Bq, 0, 1);
    f32x2 ws = __builtin_shufflevector(Bq, Bq, 2, 3);
    f32x2 dot = pk_add(pk_add(pk_mul(qx2, xs), pk_mul(qy2, ys)), pk_mul(qz2, zs));
    f32x2 s2  = pk_add(qw2, ws);
    f32x2 t2  = pk_add(dot, dot);
    float d2lo = __fsub_rn(s2.x, t2.x);
    float d2hi = __fsub_rn(s2.y, t2.y);
    if (c == qc) {                            // self-exclusion (wave-uniform branch)
      bool lo = qr < 16;
      int  tl = lo ? qr : qr - 16;
      if (l16 == tl) { if (lo) d2lo = 3.4e38f; else d2hi = 3.4e38f; }
    }
    half_pass(d2lo, c * 32);
    half_pass(d2hi, c * 32 + 16);
  }

  // lane = g*16 + l16 -> query 4wv+g entry l16 -> fully coalesced wave store
  idxout[(size_t)wv * 64 + lane] = lidx;
}

// ---------------- PointTransformerConv: one wave per point, fused output stats ----------------
// r5 structure (1024 blocks, rolled loop, dense V/S). Wave-uniform values (p, self, neighbor
// indices, neighbor coords) are forced onto the SCALAR pipe via readfirstlane: the compiler's
// divergence analysis can't prove p is uniform, so these ~54 broadcast reads per point were
// issued as vector loads competing with the 1KB S/V row gathers for VMEM slots. s_load through
// the constant cache frees the vector pipe. Values bit-identical (readfirstlane of uniform).
__global__ __launch_bounds__(256) void k_conv(const float* __restrict__ V, const float* __restrict__ S,
    const float* __restrict__ D, const float* __restrict__ pts, const int* __restrict__ idx,
    const float* __restrict__ pw, const float* __restrict__ pbv, float* __restrict__ Y,
    float* __restrict__ gsum, float* __restrict__ gss)
{
  int tid = threadIdx.x;
  int lane = tid & 63;
  int wid  = (blockIdx.x * 256 + tid) >> 6;  // 4096 waves
  int c0 = lane * 2;
  float2 w0  = *(const float2*)(pw + c0);
  float2 w1  = *(const float2*)(pw + 128 + c0);
  float2 w2  = *(const float2*)(pw + 256 + c0);
  float2 pb2 = *(const float2*)(pbv + c0);
  float st0 = 0.f, st1 = 0.f, sq0 = 0.f, sq1 = 0.f;
  for (int pv_ = wid; pv_ < PP; pv_ += 4096) {
    int p = __builtin_amdgcn_readfirstlane(pv_);   // wave-uniform -> scalar register
    int b = p >> 13, self = p & (NN - 1);
    const float* pbase = pts + (size_t)b * NN * 3;
    float pix = pbase[self*3+0], piy = pbase[self*3+1], piz = pbase[self*3+2];  // s_load
    float2 di = *(const float2*)(D + (size_t)p*128 + c0);
    const int* irow = idx + p * KNN;               // scalar base -> s_load per neighbor
    float m0 = -3.4e38f, m1 = -3.4e38f, l0 = 0.f, l1 = 0.f, a0 = 0.f, a1 = 0.f;
    for (int t = 0; t < 17; ++t) {         // 16 kNN + self loop (appended last, as in reference)
      int j = (t < 16) ? irow[t] : self;
      float dx = pix - pbase[j*3+0];
      float dy = piy - pbase[j*3+1];
      float dz = piz - pbase[j*3+2];
      size_t off = ((size_t)b * NN + j) * 128 + c0;
      float2 sj = *(const float2*)(S + off);
      float2 vj = *(const float2*)(V + off);
      float de0 = fmaf(dz, w2.x, fmaf(dy, w1.x, fmaf(dx, w0.x, pb2.x)));
      float de1 = fmaf(dz, w2.y, fmaf(dy, w1.y, fmaf(dx, w0.y, pb2.y)));
      float g0 = di.x - sj.x + de0;
      float g1 = di.y - sj.y + de1;
      float mn0 = fmaxf(m0, g0), mn1 = fmaxf(m1, g1);
      float cr0 = __expf(m0 - mn0), cr1 = __expf(m1 - mn1);
      float e0  = __expf(g0 - mn0), e1  = __expf(g1 - mn1);
      l0 = fmaf(l0, cr0, e0);
      l1 = fmaf(l1, cr1, e1);
      a0 = fmaf(a0, cr0, e0 * (vj.x + de0));
      a1 = fmaf(a1, cr1, e1 * (vj.y + de1));
      m0 = mn0; m1 = mn1;
    }
    float2 o; o.x = a0 / l0; o.y = a1 / l1;
    *(float2*)(Y + (size_t)p*128 + c0) = o;
    st0 += o.x; st1 += o.y;
    sq0 = fmaf(o.x, o.x, sq0); sq1 = fmaf(o.y, o.y, sq1);
  }
  __shared__ float cs[4][128], cq[4][128];
  int w = tid >> 6;
  cs[w][c0] = st0; cs[w][c0+1] = st1;
  cq[w][c0] = sq0; cq[w][c0+1] = sq1;
  __syncthreads();
  if (tid < 128) {
    float a  = cs[0][tid] + cs[1][tid] + cs[2][tid] + cs[3][tid];
    float b2 = cq[0][tid] + cq[1][tid] + cq[2][tid] + cq[3][tid];
    atomicAdd(gsum + tid, a);
    atomicAdd(gss  + tid, b2);
  }
}

// ---------------- decoder head: logits = relu(bn(t)) @ dec_w2 + dec_b2, inline BN ----------
__global__ __launch_bounds__(256) void k_dec2(const float* __restrict__ T,
    const float* __restrict__ gsumI, const float* __restrict__ gssI,
    const float* __restrict__ gamma, const float* __restrict__ beta,
    const float* __restrict__ W, const float* __restrict__ bias, float* __restrict__ out)
{
  __shared__ float xs[64][132];   // row stride 132 floats -> 16B-aligned float4 rows
  __shared__ float wt[13][128];
  __shared__ float scs[128], shs[128];
  int tid = threadIdx.x;
  int pb = blockIdx.x * 64;
  if (tid < 128) {                // inline BN finalize
    float mean = gsumI[tid] * (1.0f / PP);
    float var  = gssI[tid] * (1.0f / PP) - mean * mean;
    float s = gamma[tid] / sqrtf(var + 1e-5f);
    scs[tid] = s;
    shs[tid] = beta[tid] - mean * s;
  }
  __syncthreads();
  for (int i = tid; i < 13 * 128; i += 256) {
    int cls = i >> 7, k = i & 127;
    wt[cls][k] = W[k*13 + cls];
  }
  for (int i = tid; i < 64 * 32; i += 256) {
    int p = i >> 5, k = (i & 31) * 4;
    float4 v = *(const float4*)(T + (size_t)(pb + p)*128 + k);
    v.x = fmaxf(fmaf(v.x, scs[k+0], shs[k+0]), 0.f);
    v.y = fmaxf(fmaf(v.y, scs[k+1], shs[k+1]), 0.f);
    v.z = fmaxf(fmaf(v.z, scs[k+2], shs[k+2]), 0.f);
    v.w = fmaxf(fmaf(v.w, scs[k+3], shs[k+3]), 0.f);
    xs[p][k+0] = v.x; xs[p][k+1] = v.y; xs[p][k+2] = v.z; xs[p][k+3] = v.w;
  }
  __syncthreads();
  for (int o = tid; o < 64 * 13; o += 256) {
    int p = o / 13, cls = o - p * 13;
    float acc = bias[cls];
    const float4* xr = (const float4*)&xs[p][0];
    const float4* wr = (const float4*)&wt[cls][0];
    #pragma unroll 8
    for (int k4 = 0; k4 < 32; ++k4) {
      float4 a = xr[k4], w = wr[k4];
      acc = fmaf(a.x, w.x, acc);
      acc = fmaf(a.y, w.y, acc);
      acc = fmaf(a.z, w.z, acc);
      acc = fmaf(a.w, w.w, acc);
    }
    out[(size_t)(pb + p)*13 + cls] = acc;
  }
}

extern "C" void kernel_launch(void* const* d_in, const int* in_sizes, int n_in,
                              void* d_out, int out_size, void* d_ws, size_t ws_size,
                              hipStream_t stream)
{
  const float* pts      = (const float*)d_in[0];
  const float* embed_w1 = (const float*)d_in[1];
  const float* embed_b1 = (const float*)d_in[2];
  const float* bn1_g    = (const float*)d_in[3];
  const float* bn1_b    = (const float*)d_in[4];
  const float* embed_w2 = (const float*)d_in[5];
  const float* embed_b2 = (const float*)d_in[6];
  const float* bne_g    = (const float*)d_in[7];
  const float* bne_b    = (const float*)d_in[8];
  const float* l0_lin   = (const float*)d_in[9];
  const float* l0_src   = (const float*)d_in[10];
  const float* l0_dst   = (const float*)d_in[11];
  const float* l0_pos_w = (const float*)d_in[12];
  const float* l0_pos_b = (const float*)d_in[13];
  const float* l0_bn_g  = (const float*)d_in[14];
  const float* l0_bn_b  = (const float*)d_in[15];
  const float* l1_lin   = (const float*)d_in[16];
  const float* l1_src   = (const float*)d_in[17];
  const float* l1_dst   = (const float*)d_in[18];
  const float* l1_pos_w = (const float*)d_in[19];
  const float* l1_pos_b = (const float*)d_in[20];
  const float* l1_bn_g  = (const float*)d_in[21];
  const float* l1_bn_b  = (const float*)d_in[22];
  const float* dec_w1   = (const float*)d_in[23];
  const float* dec_b1   = (const float*)d_in[24];
  const float* dec_bn_g = (const float*)d_in[25];
  const float* dec_bn_b = (const float*)d_in[26];
  const float* dec_w2   = (const float*)d_in[27];
  const float* dec_b2   = (const float*)d_in[28];

  char* ws = (char*)d_ws;
  const size_t MB = 1024 * 1024;
  float* h1  = (float*)(ws + 0);          // 8 MB  [P,64]
  float* h2  = (float*)(ws + 8*MB);       // 8 MB  [P,64]
  int*   idx = (int*)  (ws + 16*MB);      // 2 MB  [P,16]
  float* v0  = (float*)(ws + 18*MB);      // 16 MB [P,128]  (reused for layer1)
  float* s0  = (float*)(ws + 34*MB);      // 16 MB
  float* d0  = (float*)(ws + 50*MB);      // 16 MB
  float* y0  = (float*)(ws + 66*MB);      // 16 MB
  float* y1  = (float*)(ws + 82*MB);      // 16 MB
  float* tt  = (float*)(ws + 0);          // 16 MB overlay on h1/h2 (dead by then)
  float* pairs8 = (float*)(ws + 18*MB);   // 512 KB overlay on v0 (dead once layer-0 proj runs)
  float* st  = (float*)(ws + 98*MB);      // 8 KB stats
  float *sum1=st+0,    *ss1=st+64;
  float *sum2=st+256,  *ss2=st+320;
  float *sum3=st+512,  *ss3=st+640;
  float *sum4=st+1024, *ss4=st+1152;
  float *sum5=st+1536, *ss5=st+1664;

  hipMemsetAsync(st, 0, 2048 * sizeof(float), stream);

  // kNN graph (runs first; pairs8 overlays v0, which is only written after k_knn completes)
  k_prep<<<64, 256, 0, stream>>>(pts, pairs8);
  k_knn<<<2048, 256, 0, stream>>>(pairs8, idx);   // 8192 waves x 4 queries

  // embedding MLP (stats fused into producers; BN finalize inlined in consumers)
  k_embed1<<<128, 256, 0, stream>>>(pts, embed_w1, embed_b1, h1, sum1, ss1);
  k_proj<64,64,true><<<dim3(512,1), 256, 0, stream>>>(h1, sum1, ss1, bn1_g, bn1_b,
      embed_w2, embed_w2, embed_w2, embed_b2, embed_b2, embed_b2, h2, h2, h2, sum2, ss2);

  // layer 0
  k_proj<64,128,false><<<dim3(512,3), 256, 0, stream>>>(h2, sum2, ss2, bne_g, bne_b,
      l0_lin, l0_src, l0_dst, nullptr, nullptr, nullptr, v0, s0, d0, nullptr, nullptr);
  k_conv<<<1024, 256, 0, stream>>>(v0, s0, d0, pts, idx, l0_pos_w, l0_pos_b, y0, sum3, ss3);

  // layer 1
  k_proj<128,128,false><<<dim3(512,3), 256, 0, stream>>>(y0, sum3, ss3, l0_bn_g, l0_bn_b,
      l1_lin, l1_src, l1_dst, nullptr, nullptr, nullptr, v0, s0, d0, nullptr, nullptr);
  k_conv<<<1024, 256, 0, stream>>>(v0, s0, d0, pts, idx, l1_pos_w, l1_pos_b, y1, sum4, ss4);

  // decoder
  k_proj<128,128,true><<<dim3(512,1), 256, 0, stream>>>(y1, sum4, ss4, l1_bn_g, l1_bn_b,
      dec_w1, dec_w1, dec_w1, dec_b1, dec_b1, dec_b1, tt, tt, tt, sum5, ss5);
  k_dec2<<<512, 256, 0, stream>>>(tt, sum5, ss5, dec_bn_g, dec_bn_b, dec_w2, dec_b2, (float*)d_out);
}